// Round 19
// baseline (118.552 us; speedup 1.0000x reference)
//
#include <hip/hip_runtime.h>

// ---------------------------------------------------------------------------
// SegformerGAT round 18: fusion A-path made pure global_load_lds (f16 concat
// pre-converted in prep_k) so the R6-validated counted-vmcnt 3-buffer loop
// applies verbatim — eliminates the plain-load/gload issue-order hazard that
// sank R13-15. BM=16/512thr/grid512 (2 blocks/CU); epilogue/lH = R17-PASS
// algebra. gemm3/gat4 (XCD swizzle): R16/R17-verbatim.
//  1 prep (concat->f16 ++ weights->f16)  2 fusion3  3 gemm3 l0  4 gat4<4>
//  5 gemm3 l1  6 gat4<1>  7 gemm3 final
// ---------------------------------------------------------------------------

#define NNODE 4096
#define LN_EPS 1e-5f
#define LOG2E 1.4426950408889634f

typedef _Float16 half8 __attribute__((ext_vector_type(8)));
typedef _Float16 half4 __attribute__((ext_vector_type(4)));
typedef _Float16 h2 __attribute__((ext_vector_type(2)));
typedef float f32x4 __attribute__((ext_vector_type(4)));

__device__ __forceinline__ float wave_reduce_sum(float v) {
    #pragma unroll
    for (int off = 32; off > 0; off >>= 1) v += __shfl_xor(v, off, 64);
    return v;
}

__device__ __forceinline__ void gload_lds16(const void* g, void* l) {
    __builtin_amdgcn_global_load_lds(
        (const __attribute__((address_space(1))) void*)g,
        (__attribute__((address_space(3))) void*)l, 16, 0, 0);
}

template<int N> __device__ __forceinline__ void waitcnt_vm() {
    if constexpr (N <= 0)      asm volatile("s_waitcnt vmcnt(0)" ::: "memory");
    else if constexpr (N == 2) asm volatile("s_waitcnt vmcnt(2)" ::: "memory");
    else if constexpr (N == 3) asm volatile("s_waitcnt vmcnt(3)" ::: "memory");
    else if constexpr (N == 4) asm volatile("s_waitcnt vmcnt(4)" ::: "memory");
    else                       asm volatile("s_waitcnt vmcnt(8)" ::: "memory");
}
__device__ __forceinline__ void barrier_raw() {
    asm volatile("s_barrier" ::: "memory");
}

// bijective XCD swizzle for grids with total % 8 == 0
__device__ __forceinline__ int xcd_swz(int lin, int total) {
    return (lin & 7) * (total >> 3) + (lin >> 3);
}

// ---------------------------------------------------------------------------
// 3-buffer counted-vmcnt MFMA f16 GEMM (R16/R17-verbatim, validated).
// OUTMODE: 1 = f16 [M,N] (swapped mfma); 2 = fp32 planar [B,N,4096].
// ---------------------------------------------------------------------------
template<int IT, int JT, int OUTMODE>
__global__ __launch_bounds__(256) void gemm3_k(
    const _Float16* __restrict__ A, const _Float16* __restrict__ W,
    const float* __restrict__ bias_lo, const float* __restrict__ bias_hi,
    int nsplit, void* __restrict__ Cout, int K, int N)
{
    constexpr int BM = 32 * IT, BN = 32 * JT;
    constexpr int CA = (BM * 4) / 256;
    constexpr int CB = (BN * 4) / 256;
    constexpr int L = CA + CB;
    __shared__ _Float16 ldsA[3][BM * 32];
    __shared__ _Float16 ldsB[3][BN * 32];

    const int tid = threadIdx.x;
    const int lin = blockIdx.y * gridDim.x + blockIdx.x;
    const int swz = xcd_swz(lin, gridDim.x * gridDim.y);
    const int m0 = (swz / gridDim.x) * BM, n0 = (swz % gridDim.x) * BN;
    const int lane = tid & 63, w = tid >> 6;
    const int fr = lane & 15, kq = lane >> 4;
    const int sq = (kq ^ (fr & 3)) * 8;
    const int wm = (w & 1) * (16 * IT), wn = (w >> 1) * (16 * JT);

    const _Float16* aP[CA]; int aC[CA];
    #pragma unroll
    for (int i = 0; i < CA; ++i) {
        const int c = i * 256 + tid, r = c >> 2, q = (c & 3) ^ (r & 3);
        aP[i] = A + (size_t)(m0 + r) * K + q * 8;
        aC[i] = c * 8;
    }
    const _Float16* bP[CB]; int bC[CB];
    #pragma unroll
    for (int i = 0; i < CB; ++i) {
        const int c = i * 256 + tid, r = c >> 2, q = (c & 3) ^ (r & 3);
        bP[i] = W + (size_t)(n0 + r) * K + q * 8;
        bC[i] = c * 8;
    }

    f32x4 acc[IT][JT] = {};
    const int NT = K >> 5;

    #pragma unroll
    for (int i = 0; i < CA; ++i) gload_lds16(aP[i], &ldsA[0][aC[i]]);
    #pragma unroll
    for (int i = 0; i < CB; ++i) gload_lds16(bP[i], &ldsB[0][bC[i]]);
    #pragma unroll
    for (int i = 0; i < CA; ++i) gload_lds16(aP[i] + 32, &ldsA[1][aC[i]]);
    #pragma unroll
    for (int i = 0; i < CB; ++i) gload_lds16(bP[i] + 32, &ldsB[1][bC[i]]);

    int bi = 0;
    for (int t = 0; t < NT; ++t) {
        if (t + 1 < NT) waitcnt_vm<L>(); else waitcnt_vm<0>();
        barrier_raw();
        if (t + 2 < NT) {
            int nb = bi + 2; if (nb >= 3) nb -= 3;
            const int k2 = (t + 2) << 5;
            #pragma unroll
            for (int i = 0; i < CA; ++i) gload_lds16(aP[i] + k2, &ldsA[nb][aC[i]]);
            #pragma unroll
            for (int i = 0; i < CB; ++i) gload_lds16(bP[i] + k2, &ldsB[nb][bC[i]]);
        }
        half8 af[IT], bf[JT];
        #pragma unroll
        for (int i = 0; i < IT; ++i)
            af[i] = *(const half8*)&ldsA[bi][(wm + i * 16 + fr) * 32 + sq];
        #pragma unroll
        for (int j = 0; j < JT; ++j)
            bf[j] = *(const half8*)&ldsB[bi][(wn + j * 16 + fr) * 32 + sq];
        #pragma unroll
        for (int i = 0; i < IT; ++i)
            #pragma unroll
            for (int j = 0; j < JT; ++j) {
                if (OUTMODE == 1)
                    acc[i][j] = __builtin_amdgcn_mfma_f32_16x16x32_f16(
                        bf[j], af[i], acc[i][j], 0, 0, 0);
                else
                    acc[i][j] = __builtin_amdgcn_mfma_f32_16x16x32_f16(
                        af[i], bf[j], acc[i][j], 0, 0, 0);
            }
        ++bi; if (bi == 3) bi = 0;
    }

    if (OUTMODE == 1) {
        #pragma unroll
        for (int i = 0; i < IT; ++i) {
            const int m = m0 + wm + i * 16 + fr;
            #pragma unroll
            for (int j = 0; j < JT; ++j) {
                const int nb4 = n0 + wn + j * 16 + kq * 4;
                const float* bp = (nb4 < nsplit) ? bias_lo + nb4
                                                 : bias_hi + (nb4 - nsplit);
                const float4 bv = *(const float4*)bp;
                half4 ov = {(_Float16)(acc[i][j][0] + bv.x),
                            (_Float16)(acc[i][j][1] + bv.y),
                            (_Float16)(acc[i][j][2] + bv.z),
                            (_Float16)(acc[i][j][3] + bv.w)};
                *(half4*)((_Float16*)Cout + (size_t)m * N + nb4) = ov;
            }
        }
    } else {
        #pragma unroll
        for (int j = 0; j < JT; ++j) {
            const int col = n0 + wn + j * 16 + fr;
            const float bc = (col < nsplit) ? bias_lo[col] : bias_hi[col - nsplit];
            #pragma unroll
            for (int i = 0; i < IT; ++i) {
                const int mrun = m0 + wm + i * 16 + kq * 4;
                const int b = mrun >> 12, node = mrun & 4095;
                float4 ov = {acc[i][j][0] + bc, acc[i][j][1] + bc,
                             acc[i][j][2] + bc, acc[i][j][3] + bc};
                *(float4*)((float*)Cout + ((size_t)(b * N + col)) * 4096 + node) = ov;
            }
        }
    }
}

// ---------------------------------------------------------------------------
// fusion3: BM=16, 512 thr, grid 512 (2 blocks/CU, LDS ~76 KB). Pure
// gload_lds A (f16 concat) + B -> gemm3's validated counted-vmcnt 3-buffer
// loop (stager wave0: 3 loads/stage -> vmcnt(3); waves 1-7: 2 -> vmcnt(2)).
// Epilogue/lH: R17-PASS BM=16 algebra. Phase 2: R12-validated (vmcnt(2)).
// ---------------------------------------------------------------------------
__global__ __launch_bounds__(512) void fusion3_k(
    const _Float16* __restrict__ Af,       // [8192][1024] concat f16
    const _Float16* __restrict__ W1, const float* __restrict__ b1,
    const float* __restrict__ g1, const float* __restrict__ be1,
    const _Float16* __restrict__ W2, const float* __restrict__ b2,
    const float* __restrict__ g2, const float* __restrict__ be2,
    _Float16* __restrict__ out)
{
    __shared__ _Float16 lA[3][16 * 32];        //  3 KB
    __shared__ _Float16 lB[3][256 * 32];       // 48 KB
    __shared__ float lC[16 * 260];             // 16.6 KB
    __shared__ _Float16 lH[8 * 512];           //  8 KB [t2][row*4+qslot][8]

    const int tid = threadIdx.x;               // 0..511, 8 waves
    const int m0 = blockIdx.x * 16;
    const int lane = tid & 63, w = tid >> 6;
    const int fr = lane & 15, kq = lane >> 4;
    const int sq = (kq ^ (fr & 3)) * 8;
    const int wc = w * 32;                     // 8 waves x 32 cols
    const bool stager = (tid < 64);            // wave 0 stages A too

    // B staging (W1, K=1024): 1024 chunks / 512 thr = 2 each (pre-swz src)
    const _Float16* bP[2]; int bC[2];
    #pragma unroll
    for (int i = 0; i < 2; ++i) {
        const int c = i * 512 + tid, r = c >> 2, q = (c & 3) ^ (r & 3);
        bP[i] = W1 + (size_t)r * 1024 + q * 8;
        bC[i] = c * 8;
    }
    // A staging: 64 chunks, threads 0..63, 1 each (pure gload_lds)
    const int arow = tid >> 2, aq = (tid & 3) ^ (arow & 3);
    const _Float16* aP = Af + (size_t)(m0 + arow) * 1024 + aq * 8;
    const int aC = tid * 8;

    f32x4 acc[2] = {};

    // ---- phase 1: K=1024, NT=32, counted-vmcnt 3-buffer ----
    if (stager) gload_lds16(aP, &lA[0][aC]);
    #pragma unroll
    for (int i = 0; i < 2; ++i) gload_lds16(bP[i], &lB[0][bC[i]]);
    if (stager) gload_lds16(aP + 32, &lA[1][aC]);
    #pragma unroll
    for (int i = 0; i < 2; ++i) gload_lds16(bP[i] + 32, &lB[1][bC[i]]);

    int bi = 0;
    for (int t = 0; t < 32; ++t) {
        if (t + 1 < 32) { if (stager) waitcnt_vm<3>(); else waitcnt_vm<2>(); }
        else            waitcnt_vm<0>();
        barrier_raw();
        if (t + 2 < 32) {
            int nb = bi + 2; if (nb >= 3) nb -= 3;
            const int k2 = (t + 2) << 5;
            if (stager) gload_lds16(aP + k2, &lA[nb][aC]);
            #pragma unroll
            for (int i = 0; i < 2; ++i) gload_lds16(bP[i] + k2, &lB[nb][bC[i]]);
        }
        const half8 af = *(const half8*)&lA[bi][fr * 32 + sq];
        half8 bf[2];
        #pragma unroll
        for (int j = 0; j < 2; ++j)
            bf[j] = *(const half8*)&lB[bi][(wc + j * 16 + fr) * 32 + sq];
        #pragma unroll
        for (int j = 0; j < 2; ++j)
            acc[j] = __builtin_amdgcn_mfma_f32_16x16x32_f16(af, bf[j], acc[j], 0, 0, 0);
        ++bi; if (bi == 3) bi = 0;
    }

    // C1 (+b1) -> lC (stride 260)
    #pragma unroll
    for (int j = 0; j < 2; ++j) {
        const int col = wc + j * 16 + fr;
        const float bc = b1[col];
        #pragma unroll
        for (int r4 = 0; r4 < 4; ++r4)
            lC[(kq * 4 + r4) * 260 + col] = acc[j][r4] + bc;
    }
    __syncthreads();

    // LN1 + ReLU -> lH (2 rows/wave; R17-PASS algebra)
    {
        const float4 gv = *(const float4*)(g1 + lane * 4);
        const float4 bv = *(const float4*)(be1 + lane * 4);
        const int t2i = lane >> 3, gq = (lane >> 1) & 3, qo = (lane & 1) * 4;
        #pragma unroll
        for (int rr = 0; rr < 2; ++rr) {
            const int row = w * 2 + rr;
            const float4 v = *(const float4*)&lC[row * 260 + lane * 4];
            float s  = v.x + v.y + v.z + v.w;
            float s2 = v.x * v.x + v.y * v.y + v.z * v.z + v.w * v.w;
            s = wave_reduce_sum(s);
            s2 = wave_reduce_sum(s2);
            const float mu  = s * (1.0f / 256.0f);
            const float var = s2 * (1.0f / 256.0f) - mu * mu;
            const float rs  = rsqrtf(var + LN_EPS);
            half4 o;
            o[0] = (_Float16)fmaxf((v.x - mu) * rs * gv.x + bv.x, 0.f);
            o[1] = (_Float16)fmaxf((v.y - mu) * rs * gv.y + bv.y, 0.f);
            o[2] = (_Float16)fmaxf((v.z - mu) * rs * gv.z + bv.z, 0.f);
            o[3] = (_Float16)fmaxf((v.w - mu) * rs * gv.w + bv.w, 0.f);
            const int qslot = gq ^ (row & 3);
            *(half4*)&lH[t2i * 512 + (row * 4 + qslot) * 8 + qo] = o;
        }
    }
    __syncthreads();

    // ---- phase 2: K=256, NT=8, A from lH, counted-vmcnt 3-buffer ----
    const _Float16* b2P[2]; int b2C[2];
    #pragma unroll
    for (int i = 0; i < 2; ++i) {
        const int c = i * 512 + tid, r = c >> 2, q = (c & 3) ^ (r & 3);
        b2P[i] = W2 + (size_t)r * 256 + q * 8;
        b2C[i] = c * 8;
    }
    f32x4 acc2[2] = {};
    #pragma unroll
    for (int i = 0; i < 2; ++i) gload_lds16(b2P[i], &lB[0][b2C[i]]);
    #pragma unroll
    for (int i = 0; i < 2; ++i) gload_lds16(b2P[i] + 32, &lB[1][b2C[i]]);

    int bi2 = 0;
    for (int t2 = 0; t2 < 8; ++t2) {
        if (t2 + 1 < 8) waitcnt_vm<2>(); else waitcnt_vm<0>();
        barrier_raw();
        if (t2 + 2 < 8) {
            int nb = bi2 + 2; if (nb >= 3) nb -= 3;
            const int k2 = (t2 + 2) << 5;
            #pragma unroll
            for (int i = 0; i < 2; ++i) gload_lds16(b2P[i] + k2, &lB[nb][b2C[i]]);
        }
        const half8 af = *(const half8*)
            &lH[t2 * 512 + (fr * 4 + (kq ^ (fr & 3))) * 8];
        half8 bf[2];
        #pragma unroll
        for (int j = 0; j < 2; ++j)
            bf[j] = *(const half8*)&lB[bi2][(wc + j * 16 + fr) * 32 + sq];
        #pragma unroll
        for (int j = 0; j < 2; ++j)
            acc2[j] = __builtin_amdgcn_mfma_f32_16x16x32_f16(af, bf[j], acc2[j], 0, 0, 0);
        ++bi2; if (bi2 == 3) bi2 = 0;
    }

    // C2 (+b2) -> lC
    __syncthreads();
    #pragma unroll
    for (int j = 0; j < 2; ++j) {
        const int col = wc + j * 16 + fr;
        const float bc = b2[col];
        #pragma unroll
        for (int r4 = 0; r4 < 4; ++r4)
            lC[(kq * 4 + r4) * 260 + col] = acc2[j][r4] + bc;
    }
    __syncthreads();

    // LN2 + ReLU -> out
    {
        const float4 gv = *(const float4*)(g2 + lane * 4);
        const float4 bv = *(const float4*)(be2 + lane * 4);
        #pragma unroll
        for (int rr = 0; rr < 2; ++rr) {
            const int row = w * 2 + rr;
            const float4 v = *(const float4*)&lC[row * 260 + lane * 4];
            float s  = v.x + v.y + v.z + v.w;
            float s2 = v.x * v.x + v.y * v.y + v.z * v.z + v.w * v.w;
            s = wave_reduce_sum(s);
            s2 = wave_reduce_sum(s2);
            const float mu  = s * (1.0f / 256.0f);
            const float var = s2 * (1.0f / 256.0f) - mu * mu;
            const float rs  = rsqrtf(var + LN_EPS);
            half4 o;
            o[0] = (_Float16)fmaxf((v.x - mu) * rs * gv.x + bv.x, 0.f);
            o[1] = (_Float16)fmaxf((v.y - mu) * rs * gv.y + bv.y, 0.f);
            o[2] = (_Float16)fmaxf((v.z - mu) * rs * gv.z + bv.z, 0.f);
            o[3] = (_Float16)fmaxf((v.w - mu) * rs * gv.w + bv.w, 0.f);
            *(half4*)(out + (size_t)(m0 + row) * 256 + lane * 4) = o;
        }
    }
}

// ---------------------------------------------------------------------------
// gat4 (R16/R17-verbatim, validated): register-resident GAT + XCD swizzle.
// ---------------------------------------------------------------------------
template<int HEADS, int LD, int XROFF, int OC>
__global__ __launch_bounds__(256) void gat4_k(
    const _Float16* __restrict__ xlr, const _Float16* __restrict__ att16,
    const float* __restrict__ bias, _Float16* __restrict__ out)
{
    const int tid = threadIdx.x, wv = tid >> 6, lane = tid & 63;
    const int g = lane >> 4, li = lane & 15;
    const int blk = xcd_swz(blockIdx.x, gridDim.x);
    const int wid = blk * 4 + wv;
    const int gi = (HEADS == 4) ? wid : wid * 4 + g;
    const int h  = (HEADS == 4) ? g : 0;
    const int node = gi & (NNODE - 1);
    const int base = gi - node;
    const int nr = node >> 6, nc = node & 63;
    const int co = h * 256 + li * 16;

    int sidx[9]; float msk[9];
    {
        const int drs[8] = {-1,-1,-1, 0, 0, 1, 1, 1};
        const int dcs[8] = {-1, 0, 1,-1, 1,-1, 0, 1};
        #pragma unroll
        for (int j = 0; j < 8; ++j) {
            const int rj = nr + drs[j], cj = nc + dcs[j];
            const bool v = ((unsigned)rj < 64u) & ((unsigned)cj < 64u);
            sidx[j] = v ? (rj * 64 + cj) : node;
            msk[j] = v ? 0.f : -1e30f;
        }
        sidx[8] = node; msk[8] = 0.f;
    }

    const _Float16* xp = xlr + (size_t)base * LD + co;

    half8 x0[9], x1[9];
    #pragma unroll
    for (int j = 0; j < 9; ++j) {
        x0[j] = *(const half8*)(xp + (size_t)sidx[j] * LD);
        x1[j] = *(const half8*)(xp + (size_t)sidx[j] * LD + 8);
    }
    const half8 xr0 = *(const half8*)(xlr + (size_t)gi * LD + XROFF + co);
    const half8 xr1 = *(const half8*)(xlr + (size_t)gi * LD + XROFF + co + 8);
    const half8 at0 = *(const half8*)(att16 + h * 256 + li * 16);
    const half8 at1 = *(const half8*)(att16 + h * 256 + li * 16 + 8);
    const h2 hz = {(_Float16)0.f, (_Float16)0.f};
    const h2 c02 = {(_Float16)0.2f, (_Float16)0.2f};

    float lg[9];
    #pragma unroll
    for (int j = 0; j < 9; ++j) {
        h2 p = hz;
        #pragma unroll
        for (int k = 0; k < 4; ++k) {
            h2 e = ((const h2*)&x0[j])[k] + ((const h2*)&xr0)[k];
            h2 tt = __builtin_elementwise_fma(
                __builtin_elementwise_min(e, hz), c02,
                __builtin_elementwise_max(e, hz));
            p = __builtin_elementwise_fma(tt, ((const h2*)&at0)[k], p);
        }
        #pragma unroll
        for (int k = 0; k < 4; ++k) {
            h2 e = ((const h2*)&x1[j])[k] + ((const h2*)&xr1)[k];
            h2 tt = __builtin_elementwise_fma(
                __builtin_elementwise_min(e, hz), c02,
                __builtin_elementwise_max(e, hz));
            p = __builtin_elementwise_fma(tt, ((const h2*)&at1)[k], p);
        }
        float pl = (float)p[0] + (float)p[1];
        pl += __shfl_xor(pl, 1, 64);
        pl += __shfl_xor(pl, 2, 64);
        pl += __shfl_xor(pl, 4, 64);
        pl += __shfl_xor(pl, 8, 64);
        lg[j] = pl + msk[j];                 // log2-domain logits
    }

    float m = lg[0];
    #pragma unroll
    for (int j = 1; j < 9; ++j) m = fmaxf(m, lg[j]);
    float pj[9], z = 0.f;
    #pragma unroll
    for (int j = 0; j < 9; ++j) { pj[j] = __builtin_amdgcn_exp2f(lg[j] - m); z += pj[j]; }
    const float inv = __builtin_amdgcn_rcpf(z);

    float acc[16];
    #pragma unroll
    for (int k = 0; k < 16; ++k) acc[k] = 0.f;
    #pragma unroll
    for (int j = 0; j < 9; ++j) {
        const float wj = pj[j];
        #pragma unroll
        for (int k = 0; k < 8; ++k) acc[k]     += wj * (float)x0[j][k];
        #pragma unroll
        for (int k = 0; k < 8; ++k) acc[8 + k] += wj * (float)x1[j][k];
    }
    float bv[16];
    #pragma unroll
    for (int q = 0; q < 4; ++q) {
        const float4 b4 = *(const float4*)(bias + h * 256 + li * 16 + q * 4);
        bv[q * 4 + 0] = b4.x; bv[q * 4 + 1] = b4.y;
        bv[q * 4 + 2] = b4.z; bv[q * 4 + 3] = b4.w;
    }
    half8 o0, o1;
    #pragma unroll
    for (int k = 0; k < 8; ++k) o0[k] = (_Float16)fmaxf(acc[k] * inv + bv[k], 0.f);
    #pragma unroll
    for (int k = 0; k < 8; ++k) o1[k] = (_Float16)fmaxf(acc[8 + k] * inv + bv[8 + k], 0.f);
    *(half8*)(out + (size_t)gi * OC + co) = o0;
    *(half8*)(out + (size_t)gi * OC + co + 8) = o1;
}

// ---------------------------------------------------------------------------
// prep: blocks [0,4096) convert concat(rgb,xm) fp32 -> f16 [8192][1024];
// blocks [4096, 4096+1474) convert weights/att (validated wconv logic).
// ---------------------------------------------------------------------------
struct WTab {
    const float* src[9];
    int startblk[10];
    int nelem[9];
    int dstoff[9];
    float scale[9];
};

__global__ __launch_bounds__(256) void prep_k(
    const float* __restrict__ rgb, const float* __restrict__ xm,
    _Float16* __restrict__ Cf16, WTab t, _Float16* __restrict__ dst)
{
    if (blockIdx.x < 4096) {                   // concat -> f16
        const int idx = blockIdx.x * 256 + threadIdx.x;
        const int m = idx >> 7;
        const int k = (idx & 127) * 8;
        const float* s = (k < 512) ? rgb + (size_t)m * 512 + k
                                   : xm  + (size_t)m * 512 + (k - 512);
        const float4 v0 = *(const float4*)s;
        const float4 v1 = *(const float4*)(s + 4);
        half8 o = {(_Float16)v0.x, (_Float16)v0.y, (_Float16)v0.z, (_Float16)v0.w,
                   (_Float16)v1.x, (_Float16)v1.y, (_Float16)v1.z, (_Float16)v1.w};
        *(half8*)(Cf16 + (size_t)m * 1024 + k) = o;
        return;
    }
    const int b = blockIdx.x - 4096;
    int s = 0;
    #pragma unroll
    for (int i = 1; i < 9; ++i) s += (b >= t.startblk[i]);
    const int e0 = (b - t.startblk[s]) * 1024 + threadIdx.x * 4;
    if (e0 >= t.nelem[s]) return;
    const float4 v = *(const float4*)(t.src[s] + e0);
    const float sc = t.scale[s];
    half4 o = {(_Float16)(v.x * sc), (_Float16)(v.y * sc),
               (_Float16)(v.z * sc), (_Float16)(v.w * sc)};
    *(half4*)(dst + t.dstoff[s] + e0) = o;
}

// ---------------------------------------------------------------------------
extern "C" void kernel_launch(void* const* d_in, const int* in_sizes, int n_in,
                              void* d_out, int out_size, void* d_ws, size_t ws_size,
                              hipStream_t stream)
{
    const float* rgb       = (const float*)d_in[0];
    const float* xm        = (const float*)d_in[1];
    const float* fusion_w  = (const float*)d_in[3];
    const float* fusion_b  = (const float*)d_in[4];
    const float* fusion_g  = (const float*)d_in[5];
    const float* fusion_be = (const float*)d_in[6];
    const float* inproj_w  = (const float*)d_in[7];
    const float* inproj_b  = (const float*)d_in[8];
    const float* norm_g    = (const float*)d_in[9];
    const float* norm_b    = (const float*)d_in[10];
    const float* l0_wl     = (const float*)d_in[11];
    const float* l0_bl     = (const float*)d_in[12];
    const float* l0_wr     = (const float*)d_in[13];
    const float* l0_br     = (const float*)d_in[14];
    const float* l0_att    = (const float*)d_in[15];
    const float* l0_bias   = (const float*)d_in[16];
    const float* l1_wl     = (const float*)d_in[17];
    const float* l1_bl     = (const float*)d_in[18];
    const float* l1_wr     = (const float*)d_in[19];
    const float* l1_br     = (const float*)d_in[20];
    const float* l1_att    = (const float*)d_in[21];
    const float* l1_bias   = (const float*)d_in[22];
    const float* fp_w      = (const float*)d_in[23];
    const float* fp_b      = (const float*)d_in[24];

    // workspace
    char* ws = (char*)d_ws;
    _Float16* Wf16 = (_Float16*)ws;                  // packed f16 weights+att
    _Float16* H1   = (_Float16*)(ws + 4194304);      //  4 MB [8192][256]
    _Float16* XLR0 = (_Float16*)(ws + 8388608);      // 32 MB [8192][2048]
    _Float16* GO0  = (_Float16*)(ws + 41943040);     // 16 MB [8192][1024]
    _Float16* XLR1 = (_Float16*)(ws + 58720256);     //  8 MB [8192][512]
    _Float16* GO1  = (_Float16*)(ws + 67108864);     //  4 MB [8192][256]
    _Float16* Cf16 = (_Float16*)(ws + 71303168);     // 16.8 MB [8192][1024]

    _Float16* w_fus  = Wf16 + 0;         // [256][1024]
    _Float16* w_inp  = Wf16 + 262144;    // [256][256]
    _Float16* w_l0   = Wf16 + 327680;    // [2048][256] (wl|wr)
    _Float16* w_l1   = Wf16 + 851968;    // [512][1024] (wl|wr)
    _Float16* w_fp   = Wf16 + 1376256;   // [512][256]
    _Float16* att0_h = Wf16 + 1507328;   // [4][256] * log2e
    _Float16* att1_h = Wf16 + 1508352;   // [1][256] * log2e

    WTab t;
    const float* srcs[9] = {fusion_w, inproj_w, l0_wl, l0_wr, l1_wl, l1_wr,
                            fp_w, l0_att, l1_att};
    const int nel[9]  = {262144, 65536, 262144, 262144, 262144, 262144,
                         131072, 1024, 256};
    const int doff[9] = {0, 262144, 327680, 589824, 851968, 1114112,
                         1376256, 1507328, 1508352};
    const int sblk[10] = {0, 256, 320, 576, 832, 1088, 1344, 1472, 1473, 1474};
    for (int i = 0; i < 9; ++i) {
        t.src[i] = srcs[i]; t.nelem[i] = nel[i]; t.dstoff[i] = doff[i];
        t.scale[i] = (i >= 7) ? LOG2E : 1.0f;
    }
    for (int i = 0; i < 10; ++i) t.startblk[i] = sblk[i];

    // 1: concat -> f16 + weights -> f16 (one dispatch)
    prep_k<<<4096 + 1474, 256, 0, stream>>>(rgb, xm, Cf16, t, Wf16);

    // 2: fusion + inproj fused -> H1  (BM=16, 512 blocks = 2/CU)
    fusion3_k<<<512, 512, 0, stream>>>(
        Cf16, w_fus, fusion_b, fusion_g, fusion_be,
        w_inp, inproj_b, norm_g, norm_b, H1);

    // 3: l0 GEMM -> XLR0 (xl|xr)   (1024 blocks, XCD-swizzled)
    gemm3_k<4, 4, 1><<<dim3(16, 64), 256, 0, stream>>>(
        H1, w_l0, l0_bl, l0_br, 1024, XLR0, 256, 2048);

    // 4: GAT h=4 -> GO0   (2048 blocks, XCD-swizzled)
    gat4_k<4, 2048, 1024, 1024><<<2048, 256, 0, stream>>>(
        XLR0, att0_h, l0_bias, GO0);

    // 5: l1 GEMM -> XLR1   (512 blocks, XCD-swizzled)
    gemm3_k<2, 4, 1><<<dim3(4, 128), 256, 0, stream>>>(
        GO0, w_l1, l1_bl, l1_br, 256, XLR1, 1024, 512);

    // 6: GAT h=1 -> GO1   (512 blocks, XCD-swizzled)
    gat4_k<1, 512, 256, 256><<<512, 256, 0, stream>>>(
        XLR1, att1_h, l1_bias, GO1);

    // 7: final -> planar [2, 512, 4096] fp32   (512 blocks, XCD-swizzled)
    gemm3_k<2, 4, 2><<<dim3(4, 128), 256, 0, stream>>>(
        GO1, w_fp, fp_b, fp_b, 512, d_out, 256, 512);
}

// Round 20
// 117.083 us; speedup vs baseline: 1.0125x; 1.0125x over previous
//
#include <hip/hip_runtime.h>

// ---------------------------------------------------------------------------
// SegformerGAT round 20: fusion4 = 1024-thread (16-wave, 4 waves/SIMD) pure-
// gload counted-vmcnt fused fusion+inproj (BM=32, grid 256). Addresses the
// 2-waves/SIMD starvation seen in all prior fusion variants. prep/gemm3/gat4:
// R18-verbatim (all validated).
//  1 prep (concat->f16 ++ weights->f16)  2 fusion4  3 gemm3 l0  4 gat4<4>
//  5 gemm3 l1  6 gat4<1>  7 gemm3 final
// ---------------------------------------------------------------------------

#define NNODE 4096
#define LN_EPS 1e-5f
#define LOG2E 1.4426950408889634f

typedef _Float16 half8 __attribute__((ext_vector_type(8)));
typedef _Float16 half4 __attribute__((ext_vector_type(4)));
typedef _Float16 h2 __attribute__((ext_vector_type(2)));
typedef float f32x4 __attribute__((ext_vector_type(4)));

__device__ __forceinline__ float wave_reduce_sum(float v) {
    #pragma unroll
    for (int off = 32; off > 0; off >>= 1) v += __shfl_xor(v, off, 64);
    return v;
}

__device__ __forceinline__ void gload_lds16(const void* g, void* l) {
    __builtin_amdgcn_global_load_lds(
        (const __attribute__((address_space(1))) void*)g,
        (__attribute__((address_space(3))) void*)l, 16, 0, 0);
}

template<int N> __device__ __forceinline__ void waitcnt_vm() {
    if constexpr (N <= 0)      asm volatile("s_waitcnt vmcnt(0)" ::: "memory");
    else if constexpr (N == 1) asm volatile("s_waitcnt vmcnt(1)" ::: "memory");
    else if constexpr (N == 2) asm volatile("s_waitcnt vmcnt(2)" ::: "memory");
    else if constexpr (N == 3) asm volatile("s_waitcnt vmcnt(3)" ::: "memory");
    else if constexpr (N == 4) asm volatile("s_waitcnt vmcnt(4)" ::: "memory");
    else                       asm volatile("s_waitcnt vmcnt(8)" ::: "memory");
}
__device__ __forceinline__ void barrier_raw() {
    asm volatile("s_barrier" ::: "memory");
}

// bijective XCD swizzle for grids with total % 8 == 0
__device__ __forceinline__ int xcd_swz(int lin, int total) {
    return (lin & 7) * (total >> 3) + (lin >> 3);
}

// ---------------------------------------------------------------------------
// 3-buffer counted-vmcnt MFMA f16 GEMM (validated R16-R18).
// OUTMODE: 1 = f16 [M,N] (swapped mfma); 2 = fp32 planar [B,N,4096].
// ---------------------------------------------------------------------------
template<int IT, int JT, int OUTMODE>
__global__ __launch_bounds__(256) void gemm3_k(
    const _Float16* __restrict__ A, const _Float16* __restrict__ W,
    const float* __restrict__ bias_lo, const float* __restrict__ bias_hi,
    int nsplit, void* __restrict__ Cout, int K, int N)
{
    constexpr int BM = 32 * IT, BN = 32 * JT;
    constexpr int CA = (BM * 4) / 256;
    constexpr int CB = (BN * 4) / 256;
    constexpr int L = CA + CB;
    __shared__ _Float16 ldsA[3][BM * 32];
    __shared__ _Float16 ldsB[3][BN * 32];

    const int tid = threadIdx.x;
    const int lin = blockIdx.y * gridDim.x + blockIdx.x;
    const int swz = xcd_swz(lin, gridDim.x * gridDim.y);
    const int m0 = (swz / gridDim.x) * BM, n0 = (swz % gridDim.x) * BN;
    const int lane = tid & 63, w = tid >> 6;
    const int fr = lane & 15, kq = lane >> 4;
    const int sq = (kq ^ (fr & 3)) * 8;
    const int wm = (w & 1) * (16 * IT), wn = (w >> 1) * (16 * JT);

    const _Float16* aP[CA]; int aC[CA];
    #pragma unroll
    for (int i = 0; i < CA; ++i) {
        const int c = i * 256 + tid, r = c >> 2, q = (c & 3) ^ (r & 3);
        aP[i] = A + (size_t)(m0 + r) * K + q * 8;
        aC[i] = c * 8;
    }
    const _Float16* bP[CB]; int bC[CB];
    #pragma unroll
    for (int i = 0; i < CB; ++i) {
        const int c = i * 256 + tid, r = c >> 2, q = (c & 3) ^ (r & 3);
        bP[i] = W + (size_t)(n0 + r) * K + q * 8;
        bC[i] = c * 8;
    }

    f32x4 acc[IT][JT] = {};
    const int NT = K >> 5;

    #pragma unroll
    for (int i = 0; i < CA; ++i) gload_lds16(aP[i], &ldsA[0][aC[i]]);
    #pragma unroll
    for (int i = 0; i < CB; ++i) gload_lds16(bP[i], &ldsB[0][bC[i]]);
    #pragma unroll
    for (int i = 0; i < CA; ++i) gload_lds16(aP[i] + 32, &ldsA[1][aC[i]]);
    #pragma unroll
    for (int i = 0; i < CB; ++i) gload_lds16(bP[i] + 32, &ldsB[1][bC[i]]);

    int bi = 0;
    for (int t = 0; t < NT; ++t) {
        if (t + 1 < NT) waitcnt_vm<L>(); else waitcnt_vm<0>();
        barrier_raw();
        if (t + 2 < NT) {
            int nb = bi + 2; if (nb >= 3) nb -= 3;
            const int k2 = (t + 2) << 5;
            #pragma unroll
            for (int i = 0; i < CA; ++i) gload_lds16(aP[i] + k2, &ldsA[nb][aC[i]]);
            #pragma unroll
            for (int i = 0; i < CB; ++i) gload_lds16(bP[i] + k2, &ldsB[nb][bC[i]]);
        }
        half8 af[IT], bf[JT];
        #pragma unroll
        for (int i = 0; i < IT; ++i)
            af[i] = *(const half8*)&ldsA[bi][(wm + i * 16 + fr) * 32 + sq];
        #pragma unroll
        for (int j = 0; j < JT; ++j)
            bf[j] = *(const half8*)&ldsB[bi][(wn + j * 16 + fr) * 32 + sq];
        #pragma unroll
        for (int i = 0; i < IT; ++i)
            #pragma unroll
            for (int j = 0; j < JT; ++j) {
                if (OUTMODE == 1)
                    acc[i][j] = __builtin_amdgcn_mfma_f32_16x16x32_f16(
                        bf[j], af[i], acc[i][j], 0, 0, 0);
                else
                    acc[i][j] = __builtin_amdgcn_mfma_f32_16x16x32_f16(
                        af[i], bf[j], acc[i][j], 0, 0, 0);
            }
        ++bi; if (bi == 3) bi = 0;
    }

    if (OUTMODE == 1) {
        #pragma unroll
        for (int i = 0; i < IT; ++i) {
            const int m = m0 + wm + i * 16 + fr;
            #pragma unroll
            for (int j = 0; j < JT; ++j) {
                const int nb4 = n0 + wn + j * 16 + kq * 4;
                const float* bp = (nb4 < nsplit) ? bias_lo + nb4
                                                 : bias_hi + (nb4 - nsplit);
                const float4 bv = *(const float4*)bp;
                half4 ov = {(_Float16)(acc[i][j][0] + bv.x),
                            (_Float16)(acc[i][j][1] + bv.y),
                            (_Float16)(acc[i][j][2] + bv.z),
                            (_Float16)(acc[i][j][3] + bv.w)};
                *(half4*)((_Float16*)Cout + (size_t)m * N + nb4) = ov;
            }
        }
    } else {
        #pragma unroll
        for (int j = 0; j < JT; ++j) {
            const int col = n0 + wn + j * 16 + fr;
            const float bc = (col < nsplit) ? bias_lo[col] : bias_hi[col - nsplit];
            #pragma unroll
            for (int i = 0; i < IT; ++i) {
                const int mrun = m0 + wm + i * 16 + kq * 4;
                const int b = mrun >> 12, node = mrun & 4095;
                float4 ov = {acc[i][j][0] + bc, acc[i][j][1] + bc,
                             acc[i][j][2] + bc, acc[i][j][3] + bc};
                *(float4*)((float*)Cout + ((size_t)(b * N + col)) * 4096 + node) = ov;
            }
        }
    }
}

// ---------------------------------------------------------------------------
// fusion4: 1024 threads (16 waves, 4/SIMD), BM=32, BN=256, grid 256.
// Pure-gload counted-vmcnt 3-buffer K-loops (R18-proven safety).
// Wave layout 2x8: wr=(w&1)*16 rows, wc=(w>>1)*32 cols; 2 MFMA/iter/wave.
// Staging: 1 chunk/thread (B: 1024 chunks; A: threads 0-127).
// Waits: one stage in flight -> stager vmcnt(2), others vmcnt(1);
// phase 2 all threads stage 1 B chunk -> vmcnt(1).
// lH/epilogue: R12-PASS BM=32 algebra.
// ---------------------------------------------------------------------------
__global__ __launch_bounds__(1024) void fusion4_k(
    const _Float16* __restrict__ Af,       // [8192][1024] concat f16
    const _Float16* __restrict__ W1, const float* __restrict__ b1,
    const float* __restrict__ g1, const float* __restrict__ be1,
    const _Float16* __restrict__ W2, const float* __restrict__ b2,
    const float* __restrict__ g2, const float* __restrict__ be2,
    _Float16* __restrict__ out)
{
    __shared__ _Float16 lA[3][32 * 32];        //  6 KB
    __shared__ _Float16 lB[3][256 * 32];       // 48 KB
    __shared__ float lC[32 * 260];             // 33.3 KB
    __shared__ _Float16 lH[8 * 1024];          // 16 KB [t2][row*4+qslot][8]

    const int tid = threadIdx.x;               // 0..1023, 16 waves
    const int m0 = blockIdx.x * 32;
    const int lane = tid & 63, w = tid >> 6;
    const int fr = lane & 15, kq = lane >> 4;
    const int sq = (kq ^ (fr & 3)) * 8;
    const int wr = (w & 1) * 16, wc = (w >> 1) * 32;   // 2 x 8 wave grid
    const bool stager = (tid < 128);

    // B staging: 1024 chunks / 1024 threads = 1 each (pre-swizzled source)
    const int bc_ = tid, br_ = bc_ >> 2, bq_ = (bc_ & 3) ^ (br_ & 3);
    const _Float16* bP = W1 + (size_t)br_ * 1024 + bq_ * 8;
    const int bC = bc_ * 8;
    // A staging: 128 chunks, threads 0..127, 1 each
    const int arow = tid >> 2, aq = (tid & 3) ^ (arow & 3);
    const _Float16* aP = Af + (size_t)(m0 + arow) * 1024 + aq * 8;
    const int aC = tid * 8;

    f32x4 acc[2] = {};

    // ---- phase 1: K=1024, NT=32, counted-vmcnt 3-buffer ----
    if (stager) gload_lds16(aP, &lA[0][aC]);
    gload_lds16(bP, &lB[0][bC]);
    if (stager) gload_lds16(aP + 32, &lA[1][aC]);
    gload_lds16(bP + 32, &lB[1][bC]);

    int bi = 0;
    for (int t = 0; t < 32; ++t) {
        if (t + 1 < 32) { if (stager) waitcnt_vm<2>(); else waitcnt_vm<1>(); }
        else            waitcnt_vm<0>();
        barrier_raw();
        if (t + 2 < 32) {
            int nb = bi + 2; if (nb >= 3) nb -= 3;
            const int k2 = (t + 2) << 5;
            if (stager) gload_lds16(aP + k2, &lA[nb][aC]);
            gload_lds16(bP + k2, &lB[nb][bC]);
        }
        const half8 af = *(const half8*)&lA[bi][(wr + fr) * 32 + sq];
        half8 bf[2];
        #pragma unroll
        for (int j = 0; j < 2; ++j)
            bf[j] = *(const half8*)&lB[bi][(wc + j * 16 + fr) * 32 + sq];
        #pragma unroll
        for (int j = 0; j < 2; ++j)
            acc[j] = __builtin_amdgcn_mfma_f32_16x16x32_f16(af, bf[j], acc[j], 0, 0, 0);
        ++bi; if (bi == 3) bi = 0;
    }

    // C1 (+b1) -> lC (stride 260)
    #pragma unroll
    for (int j = 0; j < 2; ++j) {
        const int col = wc + j * 16 + fr;
        const float bc = b1[col];
        #pragma unroll
        for (int r4 = 0; r4 < 4; ++r4)
            lC[(wr + kq * 4 + r4) * 260 + col] = acc[j][r4] + bc;
    }
    __syncthreads();

    // LN1 + ReLU -> lH (2 rows/wave; R12-PASS algebra, row in 0..32)
    {
        const float4 gv = *(const float4*)(g1 + lane * 4);
        const float4 bv = *(const float4*)(be1 + lane * 4);
        const int t2i = lane >> 3, gq = (lane >> 1) & 3, qo = (lane & 1) * 4;
        #pragma unroll
        for (int rr = 0; rr < 2; ++rr) {
            const int row = w * 2 + rr;
            const float4 v = *(const float4*)&lC[row * 260 + lane * 4];
            float s  = v.x + v.y + v.z + v.w;
            float s2 = v.x * v.x + v.y * v.y + v.z * v.z + v.w * v.w;
            s = wave_reduce_sum(s);
            s2 = wave_reduce_sum(s2);
            const float mu  = s * (1.0f / 256.0f);
            const float var = s2 * (1.0f / 256.0f) - mu * mu;
            const float rs  = rsqrtf(var + LN_EPS);
            half4 o;
            o[0] = (_Float16)fmaxf((v.x - mu) * rs * gv.x + bv.x, 0.f);
            o[1] = (_Float16)fmaxf((v.y - mu) * rs * gv.y + bv.y, 0.f);
            o[2] = (_Float16)fmaxf((v.z - mu) * rs * gv.z + bv.z, 0.f);
            o[3] = (_Float16)fmaxf((v.w - mu) * rs * gv.w + bv.w, 0.f);
            const int qslot = gq ^ (row & 3);
            *(half4*)&lH[t2i * 1024 + (row * 4 + qslot) * 8 + qo] = o;
        }
    }
    __syncthreads();

    // ---- phase 2: K=256, NT=8, A from lH, counted-vmcnt 3-buffer ----
    const int b2r = tid >> 2, b2q = (tid & 3) ^ (b2r & 3);
    const _Float16* b2P = W2 + (size_t)b2r * 256 + b2q * 8;
    f32x4 acc2[2] = {};
    gload_lds16(b2P, &lB[0][bC]);
    gload_lds16(b2P + 32, &lB[1][bC]);

    int bi2 = 0;
    for (int t2 = 0; t2 < 8; ++t2) {
        if (t2 + 1 < 8) waitcnt_vm<1>(); else waitcnt_vm<0>();
        barrier_raw();
        if (t2 + 2 < 8) {
            int nb = bi2 + 2; if (nb >= 3) nb -= 3;
            gload_lds16(b2P + ((t2 + 2) << 5), &lB[nb][bC]);
        }
        const half8 af = *(const half8*)
            &lH[t2 * 1024 + ((wr + fr) * 4 + (kq ^ (fr & 3))) * 8];
        half8 bf[2];
        #pragma unroll
        for (int j = 0; j < 2; ++j)
            bf[j] = *(const half8*)&lB[bi2][(wc + j * 16 + fr) * 32 + sq];
        #pragma unroll
        for (int j = 0; j < 2; ++j)
            acc2[j] = __builtin_amdgcn_mfma_f32_16x16x32_f16(af, bf[j], acc2[j], 0, 0, 0);
        ++bi2; if (bi2 == 3) bi2 = 0;
    }

    // C2 (+b2) -> lC
    __syncthreads();
    #pragma unroll
    for (int j = 0; j < 2; ++j) {
        const int col = wc + j * 16 + fr;
        const float bc = b2[col];
        #pragma unroll
        for (int r4 = 0; r4 < 4; ++r4)
            lC[(wr + kq * 4 + r4) * 260 + col] = acc2[j][r4] + bc;
    }
    __syncthreads();

    // LN2 + ReLU -> out
    {
        const float4 gv = *(const float4*)(g2 + lane * 4);
        const float4 bv = *(const float4*)(be2 + lane * 4);
        #pragma unroll
        for (int rr = 0; rr < 2; ++rr) {
            const int row = w * 2 + rr;
            const float4 v = *(const float4*)&lC[row * 260 + lane * 4];
            float s  = v.x + v.y + v.z + v.w;
            float s2 = v.x * v.x + v.y * v.y + v.z * v.z + v.w * v.w;
            s = wave_reduce_sum(s);
            s2 = wave_reduce_sum(s2);
            const float mu  = s * (1.0f / 256.0f);
            const float var = s2 * (1.0f / 256.0f) - mu * mu;
            const float rs  = rsqrtf(var + LN_EPS);
            half4 o;
            o[0] = (_Float16)fmaxf((v.x - mu) * rs * gv.x + bv.x, 0.f);
            o[1] = (_Float16)fmaxf((v.y - mu) * rs * gv.y + bv.y, 0.f);
            o[2] = (_Float16)fmaxf((v.z - mu) * rs * gv.z + bv.z, 0.f);
            o[3] = (_Float16)fmaxf((v.w - mu) * rs * gv.w + bv.w, 0.f);
            *(half4*)(out + (size_t)(m0 + row) * 256 + lane * 4) = o;
        }
    }
}

// ---------------------------------------------------------------------------
// gat4 (validated): register-resident GAT + XCD swizzle.
// ---------------------------------------------------------------------------
template<int HEADS, int LD, int XROFF, int OC>
__global__ __launch_bounds__(256) void gat4_k(
    const _Float16* __restrict__ xlr, const _Float16* __restrict__ att16,
    const float* __restrict__ bias, _Float16* __restrict__ out)
{
    const int tid = threadIdx.x, wv = tid >> 6, lane = tid & 63;
    const int g = lane >> 4, li = lane & 15;
    const int blk = xcd_swz(blockIdx.x, gridDim.x);
    const int wid = blk * 4 + wv;
    const int gi = (HEADS == 4) ? wid : wid * 4 + g;
    const int h  = (HEADS == 4) ? g : 0;
    const int node = gi & (NNODE - 1);
    const int base = gi - node;
    const int nr = node >> 6, nc = node & 63;
    const int co = h * 256 + li * 16;

    int sidx[9]; float msk[9];
    {
        const int drs[8] = {-1,-1,-1, 0, 0, 1, 1, 1};
        const int dcs[8] = {-1, 0, 1,-1, 1,-1, 0, 1};
        #pragma unroll
        for (int j = 0; j < 8; ++j) {
            const int rj = nr + drs[j], cj = nc + dcs[j];
            const bool v = ((unsigned)rj < 64u) & ((unsigned)cj < 64u);
            sidx[j] = v ? (rj * 64 + cj) : node;
            msk[j] = v ? 0.f : -1e30f;
        }
        sidx[8] = node; msk[8] = 0.f;
    }

    const _Float16* xp = xlr + (size_t)base * LD + co;

    half8 x0[9], x1[9];
    #pragma unroll
    for (int j = 0; j < 9; ++j) {
        x0[j] = *(const half8*)(xp + (size_t)sidx[j] * LD);
        x1[j] = *(const half8*)(xp + (size_t)sidx[j] * LD + 8);
    }
    const half8 xr0 = *(const half8*)(xlr + (size_t)gi * LD + XROFF + co);
    const half8 xr1 = *(const half8*)(xlr + (size_t)gi * LD + XROFF + co + 8);
    const half8 at0 = *(const half8*)(att16 + h * 256 + li * 16);
    const half8 at1 = *(const half8*)(att16 + h * 256 + li * 16 + 8);
    const h2 hz = {(_Float16)0.f, (_Float16)0.f};
    const h2 c02 = {(_Float16)0.2f, (_Float16)0.2f};

    float lg[9];
    #pragma unroll
    for (int j = 0; j < 9; ++j) {
        h2 p = hz;
        #pragma unroll
        for (int k = 0; k < 4; ++k) {
            h2 e = ((const h2*)&x0[j])[k] + ((const h2*)&xr0)[k];
            h2 tt = __builtin_elementwise_fma(
                __builtin_elementwise_min(e, hz), c02,
                __builtin_elementwise_max(e, hz));
            p = __builtin_elementwise_fma(tt, ((const h2*)&at0)[k], p);
        }
        #pragma unroll
        for (int k = 0; k < 4; ++k) {
            h2 e = ((const h2*)&x1[j])[k] + ((const h2*)&xr1)[k];
            h2 tt = __builtin_elementwise_fma(
                __builtin_elementwise_min(e, hz), c02,
                __builtin_elementwise_max(e, hz));
            p = __builtin_elementwise_fma(tt, ((const h2*)&at1)[k], p);
        }
        float pl = (float)p[0] + (float)p[1];
        pl += __shfl_xor(pl, 1, 64);
        pl += __shfl_xor(pl, 2, 64);
        pl += __shfl_xor(pl, 4, 64);
        pl += __shfl_xor(pl, 8, 64);
        lg[j] = pl + msk[j];                 // log2-domain logits
    }

    float m = lg[0];
    #pragma unroll
    for (int j = 1; j < 9; ++j) m = fmaxf(m, lg[j]);
    float pj[9], z = 0.f;
    #pragma unroll
    for (int j = 0; j < 9; ++j) { pj[j] = __builtin_amdgcn_exp2f(lg[j] - m); z += pj[j]; }
    const float inv = __builtin_amdgcn_rcpf(z);

    float acc[16];
    #pragma unroll
    for (int k = 0; k < 16; ++k) acc[k] = 0.f;
    #pragma unroll
    for (int j = 0; j < 9; ++j) {
        const float wj = pj[j];
        #pragma unroll
        for (int k = 0; k < 8; ++k) acc[k]     += wj * (float)x0[j][k];
        #pragma unroll
        for (int k = 0; k < 8; ++k) acc[8 + k] += wj * (float)x1[j][k];
    }
    float bv[16];
    #pragma unroll
    for (int q = 0; q < 4; ++q) {
        const float4 b4 = *(const float4*)(bias + h * 256 + li * 16 + q * 4);
        bv[q * 4 + 0] = b4.x; bv[q * 4 + 1] = b4.y;
        bv[q * 4 + 2] = b4.z; bv[q * 4 + 3] = b4.w;
    }
    half8 o0, o1;
    #pragma unroll
    for (int k = 0; k < 8; ++k) o0[k] = (_Float16)fmaxf(acc[k] * inv + bv[k], 0.f);
    #pragma unroll
    for (int k = 0; k < 8; ++k) o1[k] = (_Float16)fmaxf(acc[8 + k] * inv + bv[8 + k], 0.f);
    *(half8*)(out + (size_t)gi * OC + co) = o0;
    *(half8*)(out + (size_t)gi * OC + co + 8) = o1;
}

// ---------------------------------------------------------------------------
// prep (R18-verbatim): blocks [0,4096) concat fp32->f16; rest weights->f16.
// ---------------------------------------------------------------------------
struct WTab {
    const float* src[9];
    int startblk[10];
    int nelem[9];
    int dstoff[9];
    float scale[9];
};

__global__ __launch_bounds__(256) void prep_k(
    const float* __restrict__ rgb, const float* __restrict__ xm,
    _Float16* __restrict__ Cf16, WTab t, _Float16* __restrict__ dst)
{
    if (blockIdx.x < 4096) {                   // concat -> f16
        const int idx = blockIdx.x * 256 + threadIdx.x;
        const int m = idx >> 7;
        const int k = (idx & 127) * 8;
        const float* s = (k < 512) ? rgb + (size_t)m * 512 + k
                                   : xm  + (size_t)m * 512 + (k - 512);
        const float4 v0 = *(const float4*)s;
        const float4 v1 = *(const float4*)(s + 4);
        half8 o = {(_Float16)v0.x, (_Float16)v0.y, (_Float16)v0.z, (_Float16)v0.w,
                   (_Float16)v1.x, (_Float16)v1.y, (_Float16)v1.z, (_Float16)v1.w};
        *(half8*)(Cf16 + (size_t)m * 1024 + k) = o;
        return;
    }
    const int b = blockIdx.x - 4096;
    int s = 0;
    #pragma unroll
    for (int i = 1; i < 9; ++i) s += (b >= t.startblk[i]);
    const int e0 = (b - t.startblk[s]) * 1024 + threadIdx.x * 4;
    if (e0 >= t.nelem[s]) return;
    const float4 v = *(const float4*)(t.src[s] + e0);
    const float sc = t.scale[s];
    half4 o = {(_Float16)(v.x * sc), (_Float16)(v.y * sc),
               (_Float16)(v.z * sc), (_Float16)(v.w * sc)};
    *(half4*)(dst + t.dstoff[s] + e0) = o;
}

// ---------------------------------------------------------------------------
extern "C" void kernel_launch(void* const* d_in, const int* in_sizes, int n_in,
                              void* d_out, int out_size, void* d_ws, size_t ws_size,
                              hipStream_t stream)
{
    const float* rgb       = (const float*)d_in[0];
    const float* xm        = (const float*)d_in[1];
    const float* fusion_w  = (const float*)d_in[3];
    const float* fusion_b  = (const float*)d_in[4];
    const float* fusion_g  = (const float*)d_in[5];
    const float* fusion_be = (const float*)d_in[6];
    const float* inproj_w  = (const float*)d_in[7];
    const float* inproj_b  = (const float*)d_in[8];
    const float* norm_g    = (const float*)d_in[9];
    const float* norm_b    = (const float*)d_in[10];
    const float* l0_wl     = (const float*)d_in[11];
    const float* l0_bl     = (const float*)d_in[12];
    const float* l0_wr     = (const float*)d_in[13];
    const float* l0_br     = (const float*)d_in[14];
    const float* l0_att    = (const float*)d_in[15];
    const float* l0_bias   = (const float*)d_in[16];
    const float* l1_wl     = (const float*)d_in[17];
    const float* l1_bl     = (const float*)d_in[18];
    const float* l1_wr     = (const float*)d_in[19];
    const float* l1_br     = (const float*)d_in[20];
    const float* l1_att    = (const float*)d_in[21];
    const float* l1_bias   = (const float*)d_in[22];
    const float* fp_w      = (const float*)d_in[23];
    const float* fp_b      = (const float*)d_in[24];

    // workspace
    char* ws = (char*)d_ws;
    _Float16* Wf16 = (_Float16*)ws;                  // packed f16 weights+att
    _Float16* H1   = (_Float16*)(ws + 4194304);      //  4 MB [8192][256]
    _Float16* XLR0 = (_Float16*)(ws + 8388608);      // 32 MB [8192][2048]
    _Float16* GO0  = (_Float16*)(ws + 41943040);     // 16 MB [8192][1024]
    _Float16* XLR1 = (_Float16*)(ws + 58720256);     //  8 MB [8192][512]
    _Float16* GO1  = (_Float16*)(ws + 67108864);     //  4 MB [8192][256]
    _Float16* Cf16 = (_Float16*)(ws + 71303168);     // 16.8 MB [8192][1024]

    _Float16* w_fus  = Wf16 + 0;         // [256][1024]
    _Float16* w_inp  = Wf16 + 262144;    // [256][256]
    _Float16* w_l0   = Wf16 + 327680;    // [2048][256] (wl|wr)
    _Float16* w_l1   = Wf16 + 851968;    // [512][1024] (wl|wr)
    _Float16* w_fp   = Wf16 + 1376256;   // [512][256]
    _Float16* att0_h = Wf16 + 1507328;   // [4][256] * log2e
    _Float16* att1_h = Wf16 + 1508352;   // [1][256] * log2e

    WTab t;
    const float* srcs[9] = {fusion_w, inproj_w, l0_wl, l0_wr, l1_wl, l1_wr,
                            fp_w, l0_att, l1_att};
    const int nel[9]  = {262144, 65536, 262144, 262144, 262144, 262144,
                         131072, 1024, 256};
    const int doff[9] = {0, 262144, 327680, 589824, 851968, 1114112,
                         1376256, 1507328, 1508352};
    const int sblk[10] = {0, 256, 320, 576, 832, 1088, 1344, 1472, 1473, 1474};
    for (int i = 0; i < 9; ++i) {
        t.src[i] = srcs[i]; t.nelem[i] = nel[i]; t.dstoff[i] = doff[i];
        t.scale[i] = (i >= 7) ? LOG2E : 1.0f;
    }
    for (int i = 0; i < 10; ++i) t.startblk[i] = sblk[i];

    // 1: concat -> f16 + weights -> f16 (one dispatch)
    prep_k<<<4096 + 1474, 256, 0, stream>>>(rgb, xm, Cf16, t, Wf16);

    // 2: fusion + inproj fused -> H1  (1024 thr, 16 waves, grid 256)
    fusion4_k<<<256, 1024, 0, stream>>>(
        Cf16, w_fus, fusion_b, fusion_g, fusion_be,
        w_inp, inproj_b, norm_g, norm_b, H1);

    // 3: l0 GEMM -> XLR0 (xl|xr)   (1024 blocks, XCD-swizzled)
    gemm3_k<4, 4, 1><<<dim3(16, 64), 256, 0, stream>>>(
        H1, w_l0, l0_bl, l0_br, 1024, XLR0, 256, 2048);

    // 4: GAT h=4 -> GO0   (2048 blocks, XCD-swizzled)
    gat4_k<4, 2048, 1024, 1024><<<2048, 256, 0, stream>>>(
        XLR0, att0_h, l0_bias, GO0);

    // 5: l1 GEMM -> XLR1   (512 blocks, XCD-swizzled)
    gemm3_k<2, 4, 1><<<dim3(4, 128), 256, 0, stream>>>(
        GO0, w_l1, l1_bl, l1_br, 256, XLR1, 1024, 512);

    // 6: GAT h=1 -> GO1   (512 blocks, XCD-swizzled)
    gat4_k<1, 512, 256, 256><<<512, 256, 0, stream>>>(
        XLR1, att1_h, l1_bias, GO1);

    // 7: final -> planar [2, 512, 4096] fp32   (512 blocks, XCD-swizzled)
    gemm3_k<2, 4, 2><<<dim3(4, 128), 256, 0, stream>>>(
        GO1, w_fp, fp_b, fp_b, 512, d_out, 256, 512);
}